// Round 1
// baseline (699.483 us; speedup 1.0000x reference)
//
#include <hip/hip_runtime.h>

// Problem: EBCNN — B=8192, S=30, D=512, H=1024, L_K=3
//   feature[b] = [ max_i conv3(emb[b,:,c], w_long) | max over last-7 conv3 w_mid | emb[b,29,:] ]
//   out[b] = sum_h W2[h] * tanh( feature[b] . W1[h] )
//
// ws layout: feature bf16 [8192*1536] then W1 bf16 [1024*1536]  (~28.3 MB total)

#define B_   8192
#define S_   30
#define D_   512
#define H_   1024
#define K_   1536   // 3*D

// ---------- helpers ----------
__device__ inline unsigned short f2bf(float f) {
    unsigned int u = __float_as_uint(f);
    u += 0x7FFFu + ((u >> 16) & 1u);   // RNE (inputs are finite/normal)
    return (unsigned short)(u >> 16);
}

__device__ inline float4 fmax4(float4 a, float4 b) {
    return make_float4(fmaxf(a.x, b.x), fmaxf(a.y, b.y), fmaxf(a.z, b.z), fmaxf(a.w, b.w));
}

__device__ inline void store_bf4(unsigned short* p, float4 v) {
    ushort4 o;
    o.x = f2bf(v.x); o.y = f2bf(v.y); o.z = f2bf(v.z); o.w = f2bf(v.w);
    *(ushort4*)p = o;
}

// ---------- kernel 1: feature extraction ----------
// thread -> (b, 4 channels). Reads emb[b, 0..29, c4..c4+3] (float4, coalesced),
// sliding 3-tap window, max over 28 (long) / last 5 (mid) windows.
__global__ __launch_bounds__(256) void feat_kernel(
    const float* __restrict__ emb, const float* __restrict__ wl,
    const float* __restrict__ wm, unsigned short* __restrict__ feat)
{
    int gid = blockIdx.x * 256 + threadIdx.x;     // 0 .. B*128-1
    int b   = gid >> 7;
    int c4  = (gid & 127) << 2;                   // channel base

    const float4* base = (const float4*)(emb + (size_t)b * (S_ * D_) + c4);
    const float l0 = wl[0], l1 = wl[1], l2 = wl[2];
    const float m0 = wm[0], m1 = wm[1], m2 = wm[2];

    float4 e0 = base[0 * 128];
    float4 e1 = base[1 * 128];
    float4 vl = make_float4(-3.4e38f, -3.4e38f, -3.4e38f, -3.4e38f);
    float4 vm = vl;

    #pragma unroll
    for (int i = 0; i < 28; ++i) {
        float4 e2 = base[(i + 2) * 128];
        float4 cv;
        cv.x = e0.x * l0 + e1.x * l1 + e2.x * l2;
        cv.y = e0.y * l0 + e1.y * l1 + e2.y * l2;
        cv.z = e0.z * l0 + e1.z * l1 + e2.z * l2;
        cv.w = e0.w * l0 + e1.w * l1 + e2.w * l2;
        vl = fmax4(vl, cv);
        if (i >= 23) {                            // compile-time after unroll
            float4 cm;
            cm.x = e0.x * m0 + e1.x * m1 + e2.x * m2;
            cm.y = e0.y * m0 + e1.y * m1 + e2.y * m2;
            cm.z = e0.z * m0 + e1.z * m1 + e2.z * m2;
            cm.w = e0.w * m0 + e1.w * m1 + e2.w * m2;
            vm = fmax4(vm, cm);
        }
        e0 = e1; e1 = e2;
    }
    // e1 == emb[b, 29, c4..c4+3]  (vs)
    unsigned short* frow = feat + (size_t)b * K_;
    store_bf4(frow + c4,            vl);
    store_bf4(frow + D_ + c4,       vm);
    store_bf4(frow + 2 * D_ + c4,   e1);
}

// ---------- kernel 2: W1 fp32 -> bf16 ----------
__global__ __launch_bounds__(256) void w1conv_kernel(
    const float* __restrict__ W1, unsigned short* __restrict__ w1b)
{
    int gid = blockIdx.x * 256 + threadIdx.x;     // H_*K_/4 threads
    float4 v = ((const float4*)W1)[gid];
    ushort4 o;
    o.x = f2bf(v.x); o.y = f2bf(v.y); o.z = f2bf(v.z); o.w = f2bf(v.w);
    ((ushort4*)w1b)[gid] = o;
}

// ---------- kernel 3: GEMM (feature @ W1^T) + tanh + W2 reduce ----------
// M=8192, N=1024, K=1536. Both operands K-contiguous (B^T-style GEMM).
// 128x128 block tile, BK=32, 4 waves in 2x2, each wave 64x64 via 4x4 MFMA
// 16x16x32 bf16 tiles. global_load_lds width-16 staging (m97 structure).
// Epilogue: out[row] += sum_cols tanh(acc) * W2[col]  (quad shuffle-reduce
// + one atomicAdd per row per wave; 16 atomics per output total).

typedef __bf16 bf16x8 __attribute__((ext_vector_type(8)));
typedef float  f32x4  __attribute__((ext_vector_type(4)));

#define GL2LDS(gp, lp) __builtin_amdgcn_global_load_lds( \
    (const __attribute__((address_space(1))) void*)(gp), \
    (__attribute__((address_space(3))) void*)(lp), 16, 0, 0)

__global__ __launch_bounds__(256) void gemm_kernel(
    const unsigned short* __restrict__ A,    // feature bf16 [8192][1536]
    const unsigned short* __restrict__ Bm,   // W1 bf16 [1024][1536]
    const float* __restrict__ W2,            // [1024]
    float* __restrict__ out)                 // [8192]
{
    __shared__ unsigned short As[128 * 32];  // 8 KB
    __shared__ unsigned short Bs[128 * 32];  // 8 KB

    const int tid  = threadIdx.x;
    const int bm   = (blockIdx.x >> 3) * 128;   // 64 m-blocks
    const int bn   = (blockIdx.x & 7) * 128;    // 8 n-blocks
    const int wave = tid >> 6;
    const int lane = tid & 63;
    const int wm   = wave >> 1;                 // 0..1 (m half)
    const int wn   = wave & 1;                  // 0..1 (n half)
    const int lrow = lane & 15;
    const int quad = lane >> 4;

    f32x4 acc[4][4] = {};

    // staging: thread t loads chunk q=t and q=t+256 (16 B each) for A and B.
    // chunk q -> LDS bytes [q*16, q*16+16) ; row q>>2, k-offset (q&3)*8 elems.
    const int srow = tid >> 2;
    const int skof = (tid & 3) * 8;
    const unsigned short* a_src0 = A  + (size_t)(bm + srow) * K_ + skof;
    const unsigned short* a_src1 = a_src0 + (size_t)64 * K_;
    const unsigned short* b_src0 = Bm + (size_t)(bn + srow) * K_ + skof;
    const unsigned short* b_src1 = b_src0 + (size_t)64 * K_;
    unsigned short* a_dst0 = &As[(size_t)tid * 8];
    unsigned short* a_dst1 = &As[(size_t)(tid + 256) * 8];
    unsigned short* b_dst0 = &Bs[(size_t)tid * 8];
    unsigned short* b_dst1 = &Bs[(size_t)(tid + 256) * 8];

    for (int kt = 0; kt < K_ / 32; ++kt) {
        const int ko = kt * 32;
        GL2LDS(a_src0 + ko, a_dst0);
        GL2LDS(a_src1 + ko, a_dst1);
        GL2LDS(b_src0 + ko, b_dst0);
        GL2LDS(b_src1 + ko, b_dst1);
        __syncthreads();   // waits vmcnt(0) then barrier

        bf16x8 af[4], bf[4];
        #pragma unroll
        for (int mi = 0; mi < 4; ++mi)
            af[mi] = *(const bf16x8*)&As[(wm * 64 + mi * 16 + lrow) * 32 + quad * 8];
        #pragma unroll
        for (int ni = 0; ni < 4; ++ni)
            bf[ni] = *(const bf16x8*)&Bs[(wn * 64 + ni * 16 + lrow) * 32 + quad * 8];

        #pragma unroll
        for (int mi = 0; mi < 4; ++mi)
            #pragma unroll
            for (int ni = 0; ni < 4; ++ni)
                acc[mi][ni] = __builtin_amdgcn_mfma_f32_16x16x32_bf16(
                    af[mi], bf[ni], acc[mi][ni], 0, 0, 0);

        __syncthreads();   // protect LDS before next stage
    }

    // epilogue: C[row][col], row = bm + wm*64 + mi*16 + quad*4 + r,
    //                        col = bn + wn*64 + ni*16 + lrow
    float w2v[4];
    #pragma unroll
    for (int ni = 0; ni < 4; ++ni)
        w2v[ni] = W2[bn + wn * 64 + ni * 16 + lrow];

    #pragma unroll
    for (int mi = 0; mi < 4; ++mi) {
        #pragma unroll
        for (int r = 0; r < 4; ++r) {
            float s = 0.f;
            #pragma unroll
            for (int ni = 0; ni < 4; ++ni)
                s += tanhf(acc[mi][ni][r]) * w2v[ni];
            #pragma unroll
            for (int off = 1; off < 16; off <<= 1)
                s += __shfl_xor(s, off, 64);
            if (lrow == 0)
                atomicAdd(&out[bm + wm * 64 + mi * 16 + quad * 4 + r], s);
        }
    }
}

extern "C" void kernel_launch(void* const* d_in, const int* in_sizes, int n_in,
                              void* d_out, int out_size, void* d_ws, size_t ws_size,
                              hipStream_t stream) {
    const float* emb = (const float*)d_in[0];   // [8192,30,512]
    const float* wl  = (const float*)d_in[1];   // [3]
    const float* wm  = (const float*)d_in[2];   // [3]
    const float* W1  = (const float*)d_in[3];   // [1024,1536]
    const float* W2  = (const float*)d_in[4];   // [1,1024]
    float* out = (float*)d_out;                 // [8192]

    unsigned short* feat = (unsigned short*)d_ws;            // 8192*1536 bf16
    unsigned short* w1b  = feat + (size_t)B_ * K_;           // 1024*1536 bf16

    hipMemsetAsync(out, 0, sizeof(float) * B_, stream);      // atomics target

    hipLaunchKernelGGL(feat_kernel, dim3(B_ * (D_ / 4) / 256), dim3(256), 0, stream,
                       emb, wl, wm, feat);
    hipLaunchKernelGGL(w1conv_kernel, dim3(H_ * K_ / 4 / 256), dim3(256), 0, stream,
                       W1, w1b);
    hipLaunchKernelGGL(gemm_kernel, dim3((B_ / 128) * (H_ / 128)), dim3(256), 0, stream,
                       feat, w1b, W2, out);
}

// Round 3
// 679.510 us; speedup vs baseline: 1.0294x; 1.0294x over previous
//
#include <hip/hip_runtime.h>

// Problem: EBCNN — B=8192, S=30, D=512, H=1024, L_K=3
//   feature[b] = [ max_i conv3(emb[b,:,c], w_long) | max over last-5 windows conv3 w_mid | emb[b,29,:] ]
//   out[b] = sum_h W2[h] * tanh( feature[b] . W1[h] )
//
// ws layout: feature bf16 [8192*1536] then W1 bf16 [1024*1536]  (~28.3 MB total)
//
// R1/R2: feat_kernel rolled (#pragma unroll 4, rolling 3-reg window, nontemporal
//     loads via native ext_vector float4) to cut VGPR and run at 8 waves/SIMD —
//     streaming kernel wants TLP, not a 30-deep unroll. GEMM untouched.

#define B_   8192
#define S_   30
#define D_   512
#define H_   1024
#define K_   1536   // 3*D

typedef float nf4 __attribute__((ext_vector_type(4)));   // native float4 for builtins

// ---------- helpers ----------
__device__ inline unsigned short f2bf(float f) {
    unsigned int u = __float_as_uint(f);
    u += 0x7FFFu + ((u >> 16) & 1u);   // RNE (inputs are finite/normal)
    return (unsigned short)(u >> 16);
}

__device__ inline nf4 fmax4(nf4 a, nf4 b) {
    nf4 r;
    r.x = fmaxf(a.x, b.x); r.y = fmaxf(a.y, b.y);
    r.z = fmaxf(a.z, b.z); r.w = fmaxf(a.w, b.w);
    return r;
}

__device__ inline void store_bf4(unsigned short* p, nf4 v) {
    ushort4 o;
    o.x = f2bf(v.x); o.y = f2bf(v.y); o.z = f2bf(v.z); o.w = f2bf(v.w);
    *(ushort4*)p = o;
}

__device__ inline nf4 ntload4(const float* p) {
    return __builtin_nontemporal_load((const nf4*)p);
}

// ---------- kernel 1: feature extraction ----------
// thread -> (b, 4 channels). Reads emb[b, 0..29, c4..c4+3] (float4, coalesced),
// rolling 3-tap window; vl = max over 28 windows, vm = max over windows 23..27.
__global__ __launch_bounds__(256) void feat_kernel(
    const float* __restrict__ emb, const float* __restrict__ wl,
    const float* __restrict__ wm, unsigned short* __restrict__ feat)
{
    int gid = blockIdx.x * 256 + threadIdx.x;     // 0 .. B*128-1
    int b   = gid >> 7;
    int c4  = (gid & 127) << 2;                   // channel base

    const float* base = emb + (size_t)b * (S_ * D_) + c4;
    const float l0 = wl[0], l1 = wl[1], l2 = wl[2];
    const float m0 = wm[0], m1 = wm[1], m2 = wm[2];

    nf4 e0 = ntload4(base + 0 * D_);
    nf4 e1 = ntload4(base + 1 * D_);
    nf4 vl = {-3.4e38f, -3.4e38f, -3.4e38f, -3.4e38f};
    nf4 vm = vl;

    #pragma unroll 4
    for (int i = 0; i < 28; ++i) {
        nf4 e2 = ntload4(base + (i + 2) * D_);
        nf4 cv = e0 * l0 + e1 * l1 + e2 * l2;
        vl = fmax4(vl, cv);
        if (i >= 23) {                            // wave-uniform branch
            nf4 cm = e0 * m0 + e1 * m1 + e2 * m2;
            vm = fmax4(vm, cm);
        }
        e0 = e1; e1 = e2;
    }
    // e1 == emb[b, 29, c4..c4+3]  (vs)
    unsigned short* frow = feat + (size_t)b * K_;
    store_bf4(frow + c4,            vl);
    store_bf4(frow + D_ + c4,       vm);
    store_bf4(frow + 2 * D_ + c4,   e1);
}

// ---------- kernel 2: W1 fp32 -> bf16 ----------
__global__ __launch_bounds__(256) void w1conv_kernel(
    const float* __restrict__ W1, unsigned short* __restrict__ w1b)
{
    int gid = blockIdx.x * 256 + threadIdx.x;     // H_*K_/4 threads
    nf4 v = ((const nf4*)W1)[gid];
    ushort4 o;
    o.x = f2bf(v.x); o.y = f2bf(v.y); o.z = f2bf(v.z); o.w = f2bf(v.w);
    ((ushort4*)w1b)[gid] = o;
}

// ---------- kernel 3: GEMM (feature @ W1^T) + tanh + W2 reduce ----------
// M=8192, N=1024, K=1536. Both operands K-contiguous (B^T-style GEMM).
// 128x128 block tile, BK=32, 4 waves in 2x2, each wave 64x64 via 4x4 MFMA
// 16x16x32 bf16 tiles. global_load_lds width-16 staging (m97 structure).
// Epilogue: out[row] += sum_cols tanh(acc) * W2[col]  (quad shuffle-reduce
// + one atomicAdd per row per wave; 16 atomics per output total).

typedef __bf16 bf16x8 __attribute__((ext_vector_type(8)));
typedef float  f32x4  __attribute__((ext_vector_type(4)));

#define GL2LDS(gp, lp) __builtin_amdgcn_global_load_lds( \
    (const __attribute__((address_space(1))) void*)(gp), \
    (__attribute__((address_space(3))) void*)(lp), 16, 0, 0)

__global__ __launch_bounds__(256) void gemm_kernel(
    const unsigned short* __restrict__ A,    // feature bf16 [8192][1536]
    const unsigned short* __restrict__ Bm,   // W1 bf16 [1024][1536]
    const float* __restrict__ W2,            // [1024]
    float* __restrict__ out)                 // [8192]
{
    __shared__ unsigned short As[128 * 32];  // 8 KB
    __shared__ unsigned short Bs[128 * 32];  // 8 KB

    const int tid  = threadIdx.x;
    const int bm   = (blockIdx.x >> 3) * 128;   // 64 m-blocks
    const int bn   = (blockIdx.x & 7) * 128;    // 8 n-blocks
    const int wave = tid >> 6;
    const int lane = tid & 63;
    const int wm   = wave >> 1;                 // 0..1 (m half)
    const int wn   = wave & 1;                  // 0..1 (n half)
    const int lrow = lane & 15;
    const int quad = lane >> 4;

    f32x4 acc[4][4] = {};

    // staging: thread t loads chunk q=t and q=t+256 (16 B each) for A and B.
    // chunk q -> LDS bytes [q*16, q*16+16) ; row q>>2, k-offset (q&3)*8 elems.
    const int srow = tid >> 2;
    const int skof = (tid & 3) * 8;
    const unsigned short* a_src0 = A  + (size_t)(bm + srow) * K_ + skof;
    const unsigned short* a_src1 = a_src0 + (size_t)64 * K_;
    const unsigned short* b_src0 = Bm + (size_t)(bn + srow) * K_ + skof;
    const unsigned short* b_src1 = b_src0 + (size_t)64 * K_;
    unsigned short* a_dst0 = &As[(size_t)tid * 8];
    unsigned short* a_dst1 = &As[(size_t)(tid + 256) * 8];
    unsigned short* b_dst0 = &Bs[(size_t)tid * 8];
    unsigned short* b_dst1 = &Bs[(size_t)(tid + 256) * 8];

    for (int kt = 0; kt < K_ / 32; ++kt) {
        const int ko = kt * 32;
        GL2LDS(a_src0 + ko, a_dst0);
        GL2LDS(a_src1 + ko, a_dst1);
        GL2LDS(b_src0 + ko, b_dst0);
        GL2LDS(b_src1 + ko, b_dst1);
        __syncthreads();   // waits vmcnt(0) then barrier

        bf16x8 af[4], bf[4];
        #pragma unroll
        for (int mi = 0; mi < 4; ++mi)
            af[mi] = *(const bf16x8*)&As[(wm * 64 + mi * 16 + lrow) * 32 + quad * 8];
        #pragma unroll
        for (int ni = 0; ni < 4; ++ni)
            bf[ni] = *(const bf16x8*)&Bs[(wn * 64 + ni * 16 + lrow) * 32 + quad * 8];

        #pragma unroll
        for (int mi = 0; mi < 4; ++mi)
            #pragma unroll
            for (int ni = 0; ni < 4; ++ni)
                acc[mi][ni] = __builtin_amdgcn_mfma_f32_16x16x32_bf16(
                    af[mi], bf[ni], acc[mi][ni], 0, 0, 0);

        __syncthreads();   // protect LDS before next stage
    }

    // epilogue: C[row][col], row = bm + wm*64 + mi*16 + quad*4 + r,
    //                        col = bn + wn*64 + ni*16 + lrow
    float w2v[4];
    #pragma unroll
    for (int ni = 0; ni < 4; ++ni)
        w2v[ni] = W2[bn + wn * 64 + ni * 16 + lrow];

    #pragma unroll
    for (int mi = 0; mi < 4; ++mi) {
        #pragma unroll
        for (int r = 0; r < 4; ++r) {
            float s = 0.f;
            #pragma unroll
            for (int ni = 0; ni < 4; ++ni)
                s += tanhf(acc[mi][ni][r]) * w2v[ni];
            #pragma unroll
            for (int off = 1; off < 16; off <<= 1)
                s += __shfl_xor(s, off, 64);
            if (lrow == 0)
                atomicAdd(&out[bm + wm * 64 + mi * 16 + quad * 4 + r], s);
        }
    }
}

extern "C" void kernel_launch(void* const* d_in, const int* in_sizes, int n_in,
                              void* d_out, int out_size, void* d_ws, size_t ws_size,
                              hipStream_t stream) {
    const float* emb = (const float*)d_in[0];   // [8192,30,512]
    const float* wl  = (const float*)d_in[1];   // [3]
    const float* wm  = (const float*)d_in[2];   // [3]
    const float* W1  = (const float*)d_in[3];   // [1024,1536]
    const float* W2  = (const float*)d_in[4];   // [1,1024]
    float* out = (float*)d_out;                 // [8192]

    unsigned short* feat = (unsigned short*)d_ws;            // 8192*1536 bf16
    unsigned short* w1b  = feat + (size_t)B_ * K_;           // 1024*1536 bf16

    (void)hipMemsetAsync(out, 0, sizeof(float) * B_, stream);  // atomics target

    hipLaunchKernelGGL(feat_kernel, dim3(B_ * (D_ / 4) / 256), dim3(256), 0, stream,
                       emb, wl, wm, feat);
    hipLaunchKernelGGL(w1conv_kernel, dim3(H_ * K_ / 4 / 256), dim3(256), 0, stream,
                       W1, w1b);
    hipLaunchKernelGGL(gemm_kernel, dim3((B_ / 128) * (H_ / 128)), dim3(256), 0, stream,
                       feat, w1b, W2, out);
}

// Round 4
// 670.802 us; speedup vs baseline: 1.0428x; 1.0130x over previous
//
#include <hip/hip_runtime.h>

// Problem: EBCNN — B=8192, S=30, D=512, H=1024, L_K=3
//   feature[b] = [ max_i conv3 w_long | max last-5 conv3 w_mid | emb[b,29,:] ]
//   out[b] = sum_h W2[h] * tanh( feature[b] . W1[h] )
//
// ws layout: feature bf16 [8192*1536] then W1 bf16 [1024*1536]  (~28.3 MB)
//
// R3->R4: GEMM BK=64 (24 barriers instead of 48), XOR bank swizzle on LDS
// chunk placement (row-stride was 64B -> 8-way b128 conflicts; swizzle
// spreads across all 32 banks, 2-way = free per m136), fast tanh epilogue.
// feat/w1conv untouched (feat ~HBM-bound at ~100us).

#define B_   8192
#define S_   30
#define D_   512
#define H_   1024
#define K_   1536   // 3*D

typedef float nf4 __attribute__((ext_vector_type(4)));

// ---------- helpers ----------
__device__ inline unsigned short f2bf(float f) {
    unsigned int u = __float_as_uint(f);
    u += 0x7FFFu + ((u >> 16) & 1u);   // RNE
    return (unsigned short)(u >> 16);
}

__device__ inline nf4 fmax4(nf4 a, nf4 b) {
    nf4 r;
    r.x = fmaxf(a.x, b.x); r.y = fmaxf(a.y, b.y);
    r.z = fmaxf(a.z, b.z); r.w = fmaxf(a.w, b.w);
    return r;
}

__device__ inline void store_bf4(unsigned short* p, nf4 v) {
    ushort4 o;
    o.x = f2bf(v.x); o.y = f2bf(v.y); o.z = f2bf(v.z); o.w = f2bf(v.w);
    *(ushort4*)p = o;
}

__device__ inline nf4 ntload4(const float* p) {
    return __builtin_nontemporal_load((const nf4*)p);
}

__device__ inline float fast_tanh(float x) {
    float cx = fminf(fmaxf(x, -15.f), 15.f);
    float e = __expf(2.f * cx);            // v_exp_f32 path
    return (e - 1.f) / (e + 1.f);
}

// ---------- kernel 1: feature extraction ----------
__global__ __launch_bounds__(256) void feat_kernel(
    const float* __restrict__ emb, const float* __restrict__ wl,
    const float* __restrict__ wm, unsigned short* __restrict__ feat)
{
    int gid = blockIdx.x * 256 + threadIdx.x;     // 0 .. B*128-1
    int b   = gid >> 7;
    int c4  = (gid & 127) << 2;                   // channel base

    const float* base = emb + (size_t)b * (S_ * D_) + c4;
    const float l0 = wl[0], l1 = wl[1], l2 = wl[2];
    const float m0 = wm[0], m1 = wm[1], m2 = wm[2];

    nf4 e0 = ntload4(base + 0 * D_);
    nf4 e1 = ntload4(base + 1 * D_);
    nf4 vl = {-3.4e38f, -3.4e38f, -3.4e38f, -3.4e38f};
    nf4 vm = vl;

    #pragma unroll 4
    for (int i = 0; i < 28; ++i) {
        nf4 e2 = ntload4(base + (i + 2) * D_);
        nf4 cv = e0 * l0 + e1 * l1 + e2 * l2;
        vl = fmax4(vl, cv);
        if (i >= 23) {                            // wave-uniform branch
            nf4 cm = e0 * m0 + e1 * m1 + e2 * m2;
            vm = fmax4(vm, cm);
        }
        e0 = e1; e1 = e2;
    }
    unsigned short* frow = feat + (size_t)b * K_;
    store_bf4(frow + c4,            vl);
    store_bf4(frow + D_ + c4,       vm);
    store_bf4(frow + 2 * D_ + c4,   e1);
}

// ---------- kernel 2: W1 fp32 -> bf16 ----------
__global__ __launch_bounds__(256) void w1conv_kernel(
    const float* __restrict__ W1, unsigned short* __restrict__ w1b)
{
    int gid = blockIdx.x * 256 + threadIdx.x;     // H_*K_/4 threads
    nf4 v = ((const nf4*)W1)[gid];
    ushort4 o;
    o.x = f2bf(v.x); o.y = f2bf(v.y); o.z = f2bf(v.z); o.w = f2bf(v.w);
    ((ushort4*)w1b)[gid] = o;
}

// ---------- kernel 3: GEMM (feature @ W1^T) + tanh + W2 reduce ----------
// M=8192, N=1024, K=1536, both operands K-contiguous. 128x128 tile, BK=64,
// 4 waves 2x2, each wave 64x64 via 4x4 MFMA 16x16x32 bf16.
// LDS: 128 rows x 64 k, stored as 16B chunks; physical chunk within a row is
// XOR-swizzled: phys_j = j ^ (row&7). global_load_lds dst stays tid-linear
// (wave-uniform + lane*16 requirement); the *source* chunk is permuted.
// Fragment read (row r, chunk j=kk*4+quad) -> addr r*128B + (j^(r&7))*16B:
// banks 4*(j^(r&7)) spread over all 32 banks, 2-way over 16 lanes = free.

typedef __bf16 bf16x8 __attribute__((ext_vector_type(8)));
typedef float  f32x4  __attribute__((ext_vector_type(4)));

#define GL2LDS(gp, lp) __builtin_amdgcn_global_load_lds( \
    (const __attribute__((address_space(1))) void*)(gp), \
    (__attribute__((address_space(3))) void*)(lp), 16, 0, 0)

__global__ __launch_bounds__(256) void gemm_kernel(
    const unsigned short* __restrict__ A,    // feature bf16 [8192][1536]
    const unsigned short* __restrict__ Bm,   // W1 bf16 [1024][1536]
    const float* __restrict__ W2,            // [1024]
    float* __restrict__ out)                 // [8192]
{
    __shared__ unsigned short As[128 * 64];  // 16 KB
    __shared__ unsigned short Bs[128 * 64];  // 16 KB

    const int tid  = threadIdx.x;
    const int bm   = (blockIdx.x >> 3) * 128;   // 64 m-blocks
    const int bn   = (blockIdx.x & 7) * 128;    // 8 n-blocks
    const int lane = tid & 63;
    const int wm   = (tid >> 6) >> 1;           // 0..1 (m half)
    const int wn   = (tid >> 6) & 1;            // 0..1 (n half)
    const int lrow = lane & 15;
    const int quad = lane >> 4;

    f32x4 acc[4][4] = {};

    // staging: thread t handles chunks q = t + jj*256, jj=0..3, for A and B.
    // chunk q: row = q>>3, swizzled slot jsw = q&7 -> global j = jsw ^ (row&7).
    int s_row[4], s_jof[4];
    #pragma unroll
    for (int jj = 0; jj < 4; ++jj) {
        int q = tid + jj * 256;
        s_row[jj] = q >> 3;
        s_jof[jj] = (((q & 7) ^ (s_row[jj] & 7)) * 8);
    }

    for (int kt = 0; kt < K_ / 64; ++kt) {
        const int ko = kt * 64;
        #pragma unroll
        for (int jj = 0; jj < 4; ++jj) {
            int q = tid + jj * 256;
            GL2LDS(A  + (size_t)(bm + s_row[jj]) * K_ + ko + s_jof[jj], &As[q * 8]);
            GL2LDS(Bm + (size_t)(bn + s_row[jj]) * K_ + ko + s_jof[jj], &Bs[q * 8]);
        }
        __syncthreads();   // vmcnt(0) drain + barrier

        #pragma unroll
        for (int kk = 0; kk < 2; ++kk) {
            bf16x8 af[4], bf[4];
            const int j = kk * 4 + quad;
            #pragma unroll
            for (int mi = 0; mi < 4; ++mi) {
                int r = wm * 64 + mi * 16 + lrow;
                af[mi] = *(const bf16x8*)&As[r * 64 + ((j ^ (r & 7)) * 8)];
            }
            #pragma unroll
            for (int ni = 0; ni < 4; ++ni) {
                int r = wn * 64 + ni * 16 + lrow;
                bf[ni] = *(const bf16x8*)&Bs[r * 64 + ((j ^ (r & 7)) * 8)];
            }
            #pragma unroll
            for (int mi = 0; mi < 4; ++mi)
                #pragma unroll
                for (int ni = 0; ni < 4; ++ni)
                    acc[mi][ni] = __builtin_amdgcn_mfma_f32_16x16x32_bf16(
                        af[mi], bf[ni], acc[mi][ni], 0, 0, 0);
        }

        __syncthreads();   // protect LDS before next stage
    }

    // epilogue: row = bm + wm*64 + mi*16 + quad*4 + r, col = bn + wn*64 + ni*16 + lrow
    float w2v[4];
    #pragma unroll
    for (int ni = 0; ni < 4; ++ni)
        w2v[ni] = W2[bn + wn * 64 + ni * 16 + lrow];

    #pragma unroll
    for (int mi = 0; mi < 4; ++mi) {
        #pragma unroll
        for (int r = 0; r < 4; ++r) {
            float s = 0.f;
            #pragma unroll
            for (int ni = 0; ni < 4; ++ni)
                s += fast_tanh(acc[mi][ni][r]) * w2v[ni];
            #pragma unroll
            for (int off = 1; off < 16; off <<= 1)
                s += __shfl_xor(s, off, 64);
            if (lrow == 0)
                atomicAdd(&out[bm + wm * 64 + mi * 16 + quad * 4 + r], s);
        }
    }
}

extern "C" void kernel_launch(void* const* d_in, const int* in_sizes, int n_in,
                              void* d_out, int out_size, void* d_ws, size_t ws_size,
                              hipStream_t stream) {
    const float* emb = (const float*)d_in[0];   // [8192,30,512]
    const float* wl  = (const float*)d_in[1];   // [3]
    const float* wm  = (const float*)d_in[2];   // [3]
    const float* W1  = (const float*)d_in[3];   // [1024,1536]
    const float* W2  = (const float*)d_in[4];   // [1,1024]
    float* out = (float*)d_out;                 // [8192]

    unsigned short* feat = (unsigned short*)d_ws;            // 8192*1536 bf16
    unsigned short* w1b  = feat + (size_t)B_ * K_;           // 1024*1536 bf16

    (void)hipMemsetAsync(out, 0, sizeof(float) * B_, stream);  // atomics target

    hipLaunchKernelGGL(feat_kernel, dim3(B_ * (D_ / 4) / 256), dim3(256), 0, stream,
                       emb, wl, wm, feat);
    hipLaunchKernelGGL(w1conv_kernel, dim3(H_ * K_ / 4 / 256), dim3(256), 0, stream,
                       W1, w1b);
    hipLaunchKernelGGL(gemm_kernel, dim3((B_ / 128) * (H_ / 128)), dim3(256), 0, stream,
                       feat, w1b, W2, out);
}